// Round 1
// baseline (5989.013 us; speedup 1.0000x reference)
//
#include <hip/hip_runtime.h>

#define Nn 50000
#define Ee 800000
#define INd 512
#define Hd 64
#define OUTd 40
#define Ll 4

// h = x @ W_in + b_in   [N,512]@[512,64], 8 rows per block
__global__ __launch_bounds__(256) void k_gemm_in(
    const float* __restrict__ x, const float* __restrict__ W,
    const float* __restrict__ b, float* __restrict__ h)
{
    __shared__ float xs[8 * INd];           // 16 KB
    const int tid = threadIdx.x;
    const int row0 = blockIdx.x * 8;
    const float4* src = (const float4*)(x + (size_t)row0 * INd);
    float4* dst4 = (float4*)xs;
    #pragma unroll
    for (int i = 0; i < 4; ++i) dst4[tid + 256 * i] = src[tid + 256 * i];
    __syncthreads();
    const int r = tid >> 6;                 // 0..3 (wave-uniform)
    const int c = tid & 63;
    float acc0 = b[c], acc1 = acc0;
    const float* xr0 = xs + r * INd;
    const float* xr1 = xs + (r + 4) * INd;
    #pragma unroll 4
    for (int k = 0; k < INd; ++k) {
        const float wv = W[k * Hd + c];     // coalesced, L2-hot (128 KB)
        acc0 += xr0[k] * wv;
        acc1 += xr1[k] * wv;
    }
    h[(size_t)(row0 + r) * Hd + c] = acc0;
    h[(size_t)(row0 + r + 4) * Hd + c] = acc1;
}

// out = A @ W + b, optional relu.  A:[N,64], W:[64,64]
__global__ __launch_bounds__(256) void k_gemm64(
    const float* __restrict__ A, const float* __restrict__ W,
    const float* __restrict__ b, float* __restrict__ out, int relu_out)
{
    __shared__ float Wl[Hd * Hd];           // 16 KB
    __shared__ float As[4 * Hd];
    const int tid = threadIdx.x;
    {
        const float4* wsrc = (const float4*)W;
        float4* wdst = (float4*)Wl;
        #pragma unroll
        for (int i = 0; i < 4; ++i) wdst[tid + 256 * i] = wsrc[tid + 256 * i];
    }
    const int row0 = blockIdx.x * 4;
    if (tid < 64) ((float4*)As)[tid] = ((const float4*)(A + (size_t)row0 * Hd))[tid];
    __syncthreads();
    const int r = tid >> 6, c = tid & 63;
    float acc = b[c];
    const float* ar = As + r * Hd;
    #pragma unroll
    for (int k = 0; k < Hd; ++k) acc += ar[k] * Wl[k * Hd + c];
    if (relu_out) acc = fmaxf(acc, 0.0f);
    out[(size_t)(row0 + r) * Hd + c] = acc;
}

// hidden = h * temp[0]   (float4 over N*H)
__global__ __launch_bounds__(256) void k_init_hidden(
    const float* __restrict__ h, float* __restrict__ hidden,
    const float* __restrict__ temp)
{
    const int i = blockIdx.x * 256 + threadIdx.x;
    const float t0 = temp[0];
    float4 v = ((const float4*)h)[i];
    v.x *= t0; v.y *= t0; v.z *= t0; v.w *= t0;
    ((float4*)hidden)[i] = v;
}

// nxt[dst[e]] += m[src[e]] * w[e]   (16 threads/edge, float4 + 4 atomics)
__global__ __launch_bounds__(256) void k_scatter(
    const float* __restrict__ m, const int* __restrict__ src,
    const int* __restrict__ dst, const float* __restrict__ w,
    float* __restrict__ nxt)
{
    const int t = blockIdx.x * 256 + threadIdx.x;
    const int e = t >> 4;
    const int off = (t & 15) << 2;
    const int s = src[e];
    const int d = dst[e];
    const float wv = w[e];
    const float4 v = *(const float4*)(m + (size_t)s * Hd + off);
    float* p = nxt + (size_t)d * Hd + off;
    atomicAdd(p + 0, v.x * wv);
    atomicAdd(p + 1, v.y * wv);
    atomicAdd(p + 2, v.z * wv);
    atomicAdd(p + 3, v.w * wv);
}

// cur = relu(nxt);  hidden += cur * temp[k]
__global__ __launch_bounds__(256) void k_relu_acc(
    const float* __restrict__ nxt, float* __restrict__ cur,
    float* __restrict__ hidden, const float* __restrict__ temp, int k)
{
    const int i = blockIdx.x * 256 + threadIdx.x;
    const float tk = temp[k];
    float4 v = ((const float4*)nxt)[i];
    v.x = fmaxf(v.x, 0.f); v.y = fmaxf(v.y, 0.f);
    v.z = fmaxf(v.z, 0.f); v.w = fmaxf(v.w, 0.f);
    ((float4*)cur)[i] = v;
    float4 hv = ((float4*)hidden)[i];
    hv.x += v.x * tk; hv.y += v.y * tk; hv.z += v.z * tk; hv.w += v.w * tk;
    ((float4*)hidden)[i] = hv;
}

// ew2[e] = w[e] * cos_sim(z[src[e]], z[dst[e]])  (16 threads/edge)
__global__ __launch_bounds__(256) void k_edge_attn(
    const float* __restrict__ z, const int* __restrict__ src,
    const int* __restrict__ dst, const float* __restrict__ w,
    float* __restrict__ ew2)
{
    const int t = blockIdx.x * 256 + threadIdx.x;
    const int e = t >> 4;
    const int off = (t & 15) << 2;
    const int s = src[e];
    const int d = dst[e];
    const float4 a  = *(const float4*)(z + (size_t)s * Hd + off);
    const float4 bq = *(const float4*)(z + (size_t)d * Hd + off);
    float d12 = a.x * bq.x + a.y * bq.y + a.z * bq.z + a.w * bq.w;
    float d11 = a.x * a.x + a.y * a.y + a.z * a.z + a.w * a.w;
    float d22 = bq.x * bq.x + bq.y * bq.y + bq.z * bq.z + bq.w * bq.w;
    #pragma unroll
    for (int m = 1; m < 16; m <<= 1) {
        d12 += __shfl_xor(d12, m);
        d11 += __shfl_xor(d11, m);
        d22 += __shfl_xor(d22, m);
    }
    if ((t & 15) == 0) {
        const float n1 = fmaxf(sqrtf(d11), 1e-8f);
        const float n2 = fmaxf(sqrtf(d22), 1e-8f);
        ew2[e] = w[e] * (d12 / (n1 * n2));
    }
}

// out = A @ W_out + b_out   [N,64]@[64,40], thread per output element
__global__ __launch_bounds__(256) void k_gemm_out(
    const float* __restrict__ A, const float* __restrict__ W,
    const float* __restrict__ b, float* __restrict__ out)
{
    const int idx = blockIdx.x * 256 + threadIdx.x;
    if (idx >= Nn * OUTd) return;
    const int row = idx / OUTd;
    const int col = idx - row * OUTd;
    const float* ar = A + (size_t)row * Hd;
    float acc = b[col];
    #pragma unroll 8
    for (int k = 0; k < Hd; ++k) acc += ar[k] * W[k * OUTd + col];
    out[idx] = acc;
}

extern "C" void kernel_launch(void* const* d_in, const int* in_sizes, int n_in,
                              void* d_out, int out_size, void* d_ws, size_t ws_size,
                              hipStream_t stream)
{
    const float* x     = (const float*)d_in[0];
    const int*   src   = (const int*)d_in[1];
    const int*   dstI  = (const int*)d_in[2];
    const float* ew    = (const float*)d_in[3];
    const float* W_in  = (const float*)d_in[4];
    const float* b_in  = (const float*)d_in[5];
    const float* Ws    = (const float*)d_in[6];
    const float* bs    = (const float*)d_in[7];
    const float* temp  = (const float*)d_in[8];
    const float* We1   = (const float*)d_in[9];
    const float* be1   = (const float*)d_in[10];
    const float* We2   = (const float*)d_in[11];
    const float* be2   = (const float*)d_in[12];
    const float* W_out = (const float*)d_in[13];
    const float* b_out = (const float*)d_in[14];
    float* out = (float*)d_out;

    const size_t NH = (size_t)Nn * Hd;      // 3.2M floats
    float* ws     = (float*)d_ws;
    float* h      = ws;                     // [N,H] persists
    float* hidden = ws + NH;                // [N,H]
    float* cur    = ws + 2 * NH;            // [N,H]
    float* m      = ws + 3 * NH;            // [N,H]
    float* nxt    = ws + 4 * NH;            // [N,H]
    float* ew2    = ws + 5 * NH;            // [E]

    const dim3 b256(256);

    k_gemm_in<<<Nn / 8, b256, 0, stream>>>(x, W_in, b_in, h);

    // ---- GPR pass 1 (weights = ew) ----
    {
        k_init_hidden<<<(int)(NH / 4 / 256), b256, 0, stream>>>(h, hidden, temp);
        const float* curin = h;
        for (int i = 0; i < Ll; ++i) {
            hipMemsetAsync(nxt, 0, NH * sizeof(float), stream);
            k_gemm64<<<Nn / 4, b256, 0, stream>>>(curin, Ws + (size_t)i * Hd * Hd,
                                                  bs + (size_t)i * Hd, m, 0);
            k_scatter<<<(Ee * 16) / 256, b256, 0, stream>>>(m, src, dstI, ew, nxt);
            k_relu_acc<<<(int)(NH / 4 / 256), b256, 0, stream>>>(nxt, cur, hidden, temp, i + 1);
            curin = cur;
        }
    }

    // ---- edge attention ----
    k_gemm64<<<Nn / 4, b256, 0, stream>>>(hidden, We1, be1, m, 1);   // t = relu(.)
    k_gemm64<<<Nn / 4, b256, 0, stream>>>(m, We2, be2, cur, 0);      // z (in cur)
    k_edge_attn<<<(Ee * 16) / 256, b256, 0, stream>>>(cur, src, dstI, ew, ew2);

    // ---- GPR pass 2 (weights = ew * attn) ----
    {
        k_init_hidden<<<(int)(NH / 4 / 256), b256, 0, stream>>>(h, hidden, temp);
        const float* curin = h;
        for (int i = 0; i < Ll; ++i) {
            hipMemsetAsync(nxt, 0, NH * sizeof(float), stream);
            k_gemm64<<<Nn / 4, b256, 0, stream>>>(curin, Ws + (size_t)i * Hd * Hd,
                                                  bs + (size_t)i * Hd, m, 0);
            k_scatter<<<(Ee * 16) / 256, b256, 0, stream>>>(m, src, dstI, ew2, nxt);
            k_relu_acc<<<(int)(NH / 4 / 256), b256, 0, stream>>>(nxt, cur, hidden, temp, i + 1);
            curin = cur;
        }
    }

    k_gemm_out<<<(Nn * OUTd + 255) / 256, b256, 0, stream>>>(hidden, W_out, b_out, out);
}

// Round 2
// 1273.932 us; speedup vs baseline: 4.7012x; 4.7012x over previous
//
#include <hip/hip_runtime.h>

#define Nn 50000
#define Ee 800000
#define INd 512
#define Hd 64
#define OUTd 40
#define Ll 4

// ---------------- input GEMM: h = x @ W_in + b_in  [N,512]@[512,64] ----------
__global__ __launch_bounds__(256) void k_gemm_in(
    const float* __restrict__ x, const float* __restrict__ W,
    const float* __restrict__ b, float* __restrict__ h)
{
    __shared__ float xs[8 * INd];           // 16 KB
    const int tid = threadIdx.x;
    const int row0 = blockIdx.x * 8;
    const float4* src = (const float4*)(x + (size_t)row0 * INd);
    float4* dst4 = (float4*)xs;
    #pragma unroll
    for (int i = 0; i < 4; ++i) dst4[tid + 256 * i] = src[tid + 256 * i];
    __syncthreads();
    const int r = tid >> 6;                 // 0..3
    const int c = tid & 63;
    float acc0 = b[c], acc1 = acc0;
    const float* xr0 = xs + r * INd;
    const float* xr1 = xs + (r + 4) * INd;
    #pragma unroll 4
    for (int k = 0; k < INd; ++k) {
        const float wv = W[k * Hd + c];
        acc0 += xr0[k] * wv;
        acc1 += xr1[k] * wv;
    }
    h[(size_t)(row0 + r) * Hd + c] = acc0;
    h[(size_t)(row0 + r + 4) * Hd + c] = acc1;
}

// ---------------- small GEMM: out = A @ W + b (optional relu) ----------------
__global__ __launch_bounds__(256) void k_gemm64(
    const float* __restrict__ A, const float* __restrict__ W,
    const float* __restrict__ b, float* __restrict__ out, int relu_out)
{
    __shared__ float Wl[Hd * Hd];
    __shared__ float As[4 * Hd];
    const int tid = threadIdx.x;
    {
        const float4* wsrc = (const float4*)W;
        float4* wdst = (float4*)Wl;
        #pragma unroll
        for (int i = 0; i < 4; ++i) wdst[tid + 256 * i] = wsrc[tid + 256 * i];
    }
    const int row0 = blockIdx.x * 4;
    if (tid < 64) ((float4*)As)[tid] = ((const float4*)(A + (size_t)row0 * Hd))[tid];
    __syncthreads();
    const int r = tid >> 6, c = tid & 63;
    float acc = b[c];
    const float* ar = As + r * Hd;
    #pragma unroll
    for (int k = 0; k < Hd; ++k) acc += ar[k] * Wl[k * Hd + c];
    if (relu_out) acc = fmaxf(acc, 0.0f);
    out[(size_t)(row0 + r) * Hd + c] = acc;
}

// ---------------- hidden = h * temp[0] ---------------------------------------
__global__ __launch_bounds__(256) void k_init_hidden(
    const float* __restrict__ h, float* __restrict__ hidden,
    const float* __restrict__ temp)
{
    const int i = blockIdx.x * 256 + threadIdx.x;
    const float t0 = temp[0];
    float4 v = ((const float4*)h)[i];
    v.x *= t0; v.y *= t0; v.z *= t0; v.w *= t0;
    ((float4*)hidden)[i] = v;
}

// ---------------- CSR build --------------------------------------------------
// counts[dst[e]]++  (int atomics, L2-resident counter array)
__global__ __launch_bounds__(256) void k_count(
    const int* __restrict__ dst, int* __restrict__ counts)
{
    const int e = blockIdx.x * 256 + threadIdx.x;
    if (e < Ee) atomicAdd(&counts[dst[e]], 1);
}

// single-block exclusive scan of counts[N] -> rowptr[N+1]
__global__ __launch_bounds__(1024) void k_scan(
    const int* __restrict__ counts, int* __restrict__ rowptr)
{
    __shared__ int sdata[1024];
    const int t = threadIdx.x;
    const int chunk = (Nn + 1023) / 1024;   // 49
    const int beg = t * chunk;
    const int end = min(Nn, beg + chunk);
    int s = 0;
    for (int i = beg; i < end; ++i) s += counts[i];
    sdata[t] = s;
    __syncthreads();
    // Hillis-Steele inclusive scan
    for (int off = 1; off < 1024; off <<= 1) {
        int v = sdata[t];
        int u = (t >= off) ? sdata[t - off] : 0;
        __syncthreads();
        sdata[t] = v + u;
        __syncthreads();
    }
    int run = sdata[t] - s;                 // exclusive prefix for this thread
    for (int i = beg; i < end; ++i) {
        rowptr[i] = run;
        run += counts[i];
    }
    if (t == 0) rowptr[Nn] = sdata[1023];
}

// cursor[i] = rowptr[i]
__global__ __launch_bounds__(256) void k_copy_int(
    const int* __restrict__ a, int* __restrict__ b)
{
    const int i = blockIdx.x * 256 + threadIdx.x;
    if (i < Nn) b[i] = a[i];
}

// slot = cursor[dst[e]]++;  esrc[slot]=src[e]; eid[slot]=e
__global__ __launch_bounds__(256) void k_fill(
    const int* __restrict__ src, const int* __restrict__ dst,
    int* __restrict__ cursor, int* __restrict__ esrc, int* __restrict__ eid)
{
    const int e = blockIdx.x * 256 + threadIdx.x;
    if (e >= Ee) return;
    const int d = dst[e];
    const int slot = atomicAdd(&cursor[d], 1);
    esrc[slot] = src[e];
    eid[slot] = e;
}

// wsort[i] = w[eid[i]]
__global__ __launch_bounds__(256) void k_perm_w(
    const float* __restrict__ w, const int* __restrict__ eid,
    float* __restrict__ wsort)
{
    const int i = blockIdx.x * 256 + threadIdx.x;
    if (i < Ee) wsort[i] = w[eid[i]];
}

// ---------------- pull-mode propagate + relu + hidden accumulate -------------
// one 64-lane wave per node; lane = feature column
__global__ __launch_bounds__(256) void k_gather(
    const float* __restrict__ m, const int* __restrict__ rowptr,
    const int* __restrict__ esrc, const float* __restrict__ wsort,
    float* __restrict__ cur, float* __restrict__ hidden,
    const float* __restrict__ temp, int k)
{
    const int wave = (blockIdx.x * 256 + threadIdx.x) >> 6;
    const int lane = threadIdx.x & 63;
    if (wave >= Nn) return;
    const int beg = rowptr[wave];
    const int end = rowptr[wave + 1];
    float acc = 0.0f;
    for (int i = beg; i < end; ++i) {
        const int s = esrc[i];              // broadcast (same addr all lanes)
        const float wv = wsort[i];
        acc += m[(size_t)s * Hd + lane] * wv;   // coalesced 256B row read
    }
    acc = fmaxf(acc, 0.0f);
    const size_t o = (size_t)wave * Hd + lane;
    cur[o] = acc;
    hidden[o] += acc * temp[k];
}

// ---------------- edge attention: ew2[e] = w[e]*cos(z[src],z[dst]) -----------
__global__ __launch_bounds__(256) void k_edge_attn(
    const float* __restrict__ z, const int* __restrict__ src,
    const int* __restrict__ dst, const float* __restrict__ w,
    float* __restrict__ ew2)
{
    const int t = blockIdx.x * 256 + threadIdx.x;
    const int e = t >> 4;
    if (e >= Ee) return;
    const int off = (t & 15) << 2;
    const int s = src[e];
    const int d = dst[e];
    const float4 a  = *(const float4*)(z + (size_t)s * Hd + off);
    const float4 bq = *(const float4*)(z + (size_t)d * Hd + off);
    float d12 = a.x * bq.x + a.y * bq.y + a.z * bq.z + a.w * bq.w;
    float d11 = a.x * a.x + a.y * a.y + a.z * a.z + a.w * a.w;
    float d22 = bq.x * bq.x + bq.y * bq.y + bq.z * bq.z + bq.w * bq.w;
    #pragma unroll
    for (int mm = 1; mm < 16; mm <<= 1) {
        d12 += __shfl_xor(d12, mm);
        d11 += __shfl_xor(d11, mm);
        d22 += __shfl_xor(d22, mm);
    }
    if ((t & 15) == 0) {
        const float n1 = fmaxf(sqrtf(d11), 1e-8f);
        const float n2 = fmaxf(sqrtf(d22), 1e-8f);
        ew2[e] = w[e] * (d12 / (n1 * n2));
    }
}

// ---------------- out = A @ W_out + b_out  [N,64]@[64,40] --------------------
__global__ __launch_bounds__(256) void k_gemm_out(
    const float* __restrict__ A, const float* __restrict__ W,
    const float* __restrict__ b, float* __restrict__ out)
{
    const int idx = blockIdx.x * 256 + threadIdx.x;
    if (idx >= Nn * OUTd) return;
    const int row = idx / OUTd;
    const int col = idx - row * OUTd;
    const float* ar = A + (size_t)row * Hd;
    float acc = b[col];
    #pragma unroll 8
    for (int k = 0; k < Hd; ++k) acc += ar[k] * W[k * OUTd + col];
    out[idx] = acc;
}

extern "C" void kernel_launch(void* const* d_in, const int* in_sizes, int n_in,
                              void* d_out, int out_size, void* d_ws, size_t ws_size,
                              hipStream_t stream)
{
    const float* x     = (const float*)d_in[0];
    const int*   src   = (const int*)d_in[1];
    const int*   dstI  = (const int*)d_in[2];
    const float* ew    = (const float*)d_in[3];
    const float* W_in  = (const float*)d_in[4];
    const float* b_in  = (const float*)d_in[5];
    const float* Ws    = (const float*)d_in[6];
    const float* bs    = (const float*)d_in[7];
    const float* temp  = (const float*)d_in[8];
    const float* We1   = (const float*)d_in[9];
    const float* be1   = (const float*)d_in[10];
    const float* We2   = (const float*)d_in[11];
    const float* be2   = (const float*)d_in[12];
    const float* W_out = (const float*)d_in[13];
    const float* b_out = (const float*)d_in[14];
    float* out = (float*)d_out;

    const size_t NH = (size_t)Nn * Hd;      // 3.2M floats
    float* ws     = (float*)d_ws;
    float* h      = ws;                     // [N,H]
    float* hidden = ws + NH;                // [N,H]
    float* cur    = ws + 2 * NH;            // [N,H]
    float* m      = ws + 3 * NH;            // [N,H]
    float* ew2    = ws + 4 * NH;            // [E]
    float* wsort  = ew2 + Ee;               // [E]
    int* ibase    = (int*)(wsort + Ee);
    int* counts   = ibase;                  // [N]   (counts, then cursor)
    int* rowptr   = ibase + Nn;             // [N+1]
    int* esrc     = rowptr + Nn + 1;        // [E]
    int* eid      = esrc + Ee;              // [E]

    const dim3 b256(256);
    const int gE   = (Ee + 255) / 256;      // 3125
    const int gNH4 = (int)(NH / 4 / 256);
    const int gW   = (Nn * 64) / 256;       // 12500 (wave per node)

    // ---- CSR build (graph is identical for both passes) ----
    hipMemsetAsync(counts, 0, Nn * sizeof(int), stream);
    k_count<<<gE, b256, 0, stream>>>(dstI, counts);
    k_scan<<<1, 1024, 0, stream>>>(counts, rowptr);
    k_copy_int<<<(Nn + 255) / 256, b256, 0, stream>>>(rowptr, counts); // cursor
    k_fill<<<gE, b256, 0, stream>>>(src, dstI, counts, esrc, eid);

    k_gemm_in<<<Nn / 8, b256, 0, stream>>>(x, W_in, b_in, h);

    // ---- GPR pass 1 (weights = ew) ----
    k_perm_w<<<gE, b256, 0, stream>>>(ew, eid, wsort);
    k_init_hidden<<<gNH4, b256, 0, stream>>>(h, hidden, temp);
    {
        const float* curin = h;
        for (int i = 0; i < Ll; ++i) {
            k_gemm64<<<Nn / 4, b256, 0, stream>>>(curin, Ws + (size_t)i * Hd * Hd,
                                                  bs + (size_t)i * Hd, m, 0);
            k_gather<<<gW, b256, 0, stream>>>(m, rowptr, esrc, wsort, cur, hidden,
                                              temp, i + 1);
            curin = cur;
        }
    }

    // ---- edge attention ----
    k_gemm64<<<Nn / 4, b256, 0, stream>>>(hidden, We1, be1, m, 1);
    k_gemm64<<<Nn / 4, b256, 0, stream>>>(m, We2, be2, cur, 0);      // z in cur
    k_edge_attn<<<(Ee * 16 + 255) / 256, b256, 0, stream>>>(cur, src, dstI, ew, ew2);

    // ---- GPR pass 2 (weights = ew * attn) ----
    k_perm_w<<<gE, b256, 0, stream>>>(ew2, eid, wsort);
    k_init_hidden<<<gNH4, b256, 0, stream>>>(h, hidden, temp);
    {
        const float* curin = h;
        for (int i = 0; i < Ll; ++i) {
            k_gemm64<<<Nn / 4, b256, 0, stream>>>(curin, Ws + (size_t)i * Hd * Hd,
                                                  bs + (size_t)i * Hd, m, 0);
            k_gather<<<gW, b256, 0, stream>>>(m, rowptr, esrc, wsort, cur, hidden,
                                              temp, i + 1);
            curin = cur;
        }
    }

    k_gemm_out<<<(Nn * OUTd + 255) / 256, b256, 0, stream>>>(hidden, W_out, b_out, out);
}

// Round 3
// 1100.654 us; speedup vs baseline: 5.4413x; 1.1574x over previous
//
#include <hip/hip_runtime.h>

#define Nn 50000
#define Ee 800000
#define INd 512
#define Hd 64
#define OUTd 40
#define Ll 4

typedef unsigned int uint;
typedef unsigned short ushort_t;

__device__ __forceinline__ float bf2f(ushort_t u) {
    return __uint_as_float(((uint)u) << 16);
}
__device__ __forceinline__ ushort_t f2bf(float f) {
    uint u = __float_as_uint(f);
    uint r = (u + 0x7fffu + ((u >> 16) & 1u)) >> 16;   // RNE
    return (ushort_t)r;
}

// ---------------- input GEMM: h = x @ W_in + b_in  [N,512]@[512,64] ----------
// 16 rows/block, 4 accumulators/thread, float4 LDS A-reads, k-unroll 4
__global__ __launch_bounds__(256) void k_gemm_in(
    const float* __restrict__ x, const float* __restrict__ W,
    const float* __restrict__ b, float* __restrict__ h)
{
    __shared__ float xs[16 * INd];          // 32 KB
    const int tid = threadIdx.x;
    const int row0 = blockIdx.x * 16;
    {
        const float4* src4 = (const float4*)(x + (size_t)row0 * INd);
        float4* dst4 = (float4*)xs;
        #pragma unroll
        for (int i = 0; i < 8; ++i) dst4[tid + 256 * i] = src4[tid + 256 * i];
    }
    __syncthreads();
    const int r = tid >> 6;                 // 0..3
    const int c = tid & 63;
    const float bc = b[c];
    float acc0 = bc, acc1 = bc, acc2 = bc, acc3 = bc;
    const float* xr0 = xs + (r     ) * INd;
    const float* xr1 = xs + (r + 4 ) * INd;
    const float* xr2 = xs + (r + 8 ) * INd;
    const float* xr3 = xs + (r + 12) * INd;
    #pragma unroll 4
    for (int k4 = 0; k4 < INd; k4 += 4) {
        const float w0 = W[(k4 + 0) * Hd + c];
        const float w1 = W[(k4 + 1) * Hd + c];
        const float w2 = W[(k4 + 2) * Hd + c];
        const float w3 = W[(k4 + 3) * Hd + c];
        float4 a0 = *(const float4*)(xr0 + k4);
        float4 a1 = *(const float4*)(xr1 + k4);
        float4 a2 = *(const float4*)(xr2 + k4);
        float4 a3 = *(const float4*)(xr3 + k4);
        acc0 += a0.x * w0 + a0.y * w1 + a0.z * w2 + a0.w * w3;
        acc1 += a1.x * w0 + a1.y * w1 + a1.z * w2 + a1.w * w3;
        acc2 += a2.x * w0 + a2.y * w1 + a2.z * w2 + a2.w * w3;
        acc3 += a3.x * w0 + a3.y * w1 + a3.z * w2 + a3.w * w3;
    }
    h[(size_t)(row0 + r     ) * Hd + c] = acc0;
    h[(size_t)(row0 + r + 4 ) * Hd + c] = acc1;
    h[(size_t)(row0 + r + 8 ) * Hd + c] = acc2;
    h[(size_t)(row0 + r + 12) * Hd + c] = acc3;
}

// ---------------- small GEMM: [N,64]@[64,64]+b, mode 0=f32 1=f32+relu 2=bf16 --
__global__ __launch_bounds__(256) void k_gemm64(
    const float* __restrict__ A, const float* __restrict__ W,
    const float* __restrict__ b, float* __restrict__ outf,
    ushort_t* __restrict__ outb, int mode)
{
    __shared__ float Wl[Hd * Hd];           // 16 KB
    __shared__ float As[16 * Hd];           // 4 KB
    const int tid = threadIdx.x;
    {
        const float4* wsrc = (const float4*)W;
        float4* wdst = (float4*)Wl;
        #pragma unroll
        for (int i = 0; i < 4; ++i) wdst[tid + 256 * i] = wsrc[tid + 256 * i];
    }
    const int row0 = blockIdx.x * 16;
    ((float4*)As)[tid] = ((const float4*)(A + (size_t)row0 * Hd))[tid];
    __syncthreads();
    const int r = tid >> 6, c = tid & 63;
    const float bc = b[c];
    float acc0 = bc, acc1 = bc, acc2 = bc, acc3 = bc;
    const float* ar0 = As + (r     ) * Hd;
    const float* ar1 = As + (r + 4 ) * Hd;
    const float* ar2 = As + (r + 8 ) * Hd;
    const float* ar3 = As + (r + 12) * Hd;
    #pragma unroll
    for (int k4 = 0; k4 < Hd; k4 += 4) {
        const float w0 = Wl[(k4 + 0) * Hd + c];
        const float w1 = Wl[(k4 + 1) * Hd + c];
        const float w2 = Wl[(k4 + 2) * Hd + c];
        const float w3 = Wl[(k4 + 3) * Hd + c];
        float4 a0 = *(const float4*)(ar0 + k4);
        float4 a1 = *(const float4*)(ar1 + k4);
        float4 a2 = *(const float4*)(ar2 + k4);
        float4 a3 = *(const float4*)(ar3 + k4);
        acc0 += a0.x * w0 + a0.y * w1 + a0.z * w2 + a0.w * w3;
        acc1 += a1.x * w0 + a1.y * w1 + a1.z * w2 + a1.w * w3;
        acc2 += a2.x * w0 + a2.y * w1 + a2.z * w2 + a2.w * w3;
        acc3 += a3.x * w0 + a3.y * w1 + a3.z * w2 + a3.w * w3;
    }
    if (mode == 1) {
        acc0 = fmaxf(acc0, 0.f); acc1 = fmaxf(acc1, 0.f);
        acc2 = fmaxf(acc2, 0.f); acc3 = fmaxf(acc3, 0.f);
    }
    if (mode == 2) {
        outb[(size_t)(row0 + r     ) * Hd + c] = f2bf(acc0);
        outb[(size_t)(row0 + r + 4 ) * Hd + c] = f2bf(acc1);
        outb[(size_t)(row0 + r + 8 ) * Hd + c] = f2bf(acc2);
        outb[(size_t)(row0 + r + 12) * Hd + c] = f2bf(acc3);
    } else {
        outf[(size_t)(row0 + r     ) * Hd + c] = acc0;
        outf[(size_t)(row0 + r + 4 ) * Hd + c] = acc1;
        outf[(size_t)(row0 + r + 8 ) * Hd + c] = acc2;
        outf[(size_t)(row0 + r + 12) * Hd + c] = acc3;
    }
}

// ---------------- CSR build --------------------------------------------------
__global__ __launch_bounds__(256) void k_count(
    const int* __restrict__ dst, int* __restrict__ counts)
{
    const int e = blockIdx.x * 256 + threadIdx.x;
    if (e < Ee) atomicAdd(&counts[dst[e]], 1);
}

__global__ __launch_bounds__(1024) void k_scan(
    const int* __restrict__ counts, int* __restrict__ rowptr)
{
    __shared__ int sdata[1024];
    const int t = threadIdx.x;
    const int chunk = (Nn + 1023) / 1024;
    const int beg = t * chunk;
    const int end = min(Nn, beg + chunk);
    int s = 0;
    for (int i = beg; i < end; ++i) s += counts[i];
    sdata[t] = s;
    __syncthreads();
    for (int off = 1; off < 1024; off <<= 1) {
        int v = sdata[t];
        int u = (t >= off) ? sdata[t - off] : 0;
        __syncthreads();
        sdata[t] = v + u;
        __syncthreads();
    }
    int run = sdata[t] - s;
    for (int i = beg; i < end; ++i) {
        rowptr[i] = run;
        run += counts[i];
    }
    if (t == 0) rowptr[Nn] = sdata[1023];
}

__global__ __launch_bounds__(256) void k_copy_int(
    const int* __restrict__ a, int* __restrict__ b)
{
    const int i = blockIdx.x * 256 + threadIdx.x;
    if (i < Nn) b[i] = a[i];
}

// slot = cursor[dst[e]]++;  ep[slot] = {src, bits(w)};  eid[slot] = e
__global__ __launch_bounds__(256) void k_fill(
    const int* __restrict__ src, const int* __restrict__ dst,
    const float* __restrict__ w, int* __restrict__ cursor,
    int2* __restrict__ ep, int* __restrict__ eid)
{
    const int e = blockIdx.x * 256 + threadIdx.x;
    if (e >= Ee) return;
    const int d = dst[e];
    const int slot = atomicAdd(&cursor[d], 1);
    ep[slot] = make_int2(src[e], __float_as_int(w[e]));
    eid[slot] = e;
}

// ep[i].y = bits(w2[eid[i]])
__global__ __launch_bounds__(256) void k_repack(
    const float* __restrict__ w2, const int* __restrict__ eid,
    int2* __restrict__ ep)
{
    const int i = blockIdx.x * 256 + threadIdx.x;
    if (i < Ee) ep[i].y = __float_as_int(w2[eid[i]]);
}

// ---------------- pull gather + relu + hidden accumulate (bf16 table) --------
__global__ __launch_bounds__(256) void k_gather(
    const ushort_t* __restrict__ mb, const int* __restrict__ rowptr,
    const int2* __restrict__ ep, const float* __restrict__ h,
    float* __restrict__ cur, float* __restrict__ hidden,
    const float* __restrict__ temp, int k)
{
    const int wave = (blockIdx.x * 256 + threadIdx.x) >> 6;
    const int lane = threadIdx.x & 63;
    if (wave >= Nn) return;
    const int beg = rowptr[wave];
    const int end = rowptr[wave + 1];
    float acc = 0.0f;
    for (int i = beg; i < end; ++i) {
        const int2 e = ep[i];                        // broadcast 8B
        const float wv = __int_as_float(e.y);
        acc += bf2f(mb[(size_t)e.x * Hd + lane]) * wv;   // 128B coalesced row
    }
    acc = fmaxf(acc, 0.0f);
    const size_t o = (size_t)wave * Hd + lane;
    cur[o] = acc;
    if (k == 1) hidden[o] = h[o] * temp[0] + acc * temp[1];
    else        hidden[o] += acc * temp[k];
}

// ---------------- edge attention on bf16 z: 8 threads/edge -------------------
__device__ __forceinline__ void dot2(uint ua, uint ub,
                                     float& d12, float& d11, float& d22)
{
    const float al = __uint_as_float(ua << 16);
    const float ah = __uint_as_float(ua & 0xffff0000u);
    const float bl = __uint_as_float(ub << 16);
    const float bh = __uint_as_float(ub & 0xffff0000u);
    d12 += al * bl + ah * bh;
    d11 += al * al + ah * ah;
    d22 += bl * bl + bh * bh;
}

__global__ __launch_bounds__(256) void k_edge_attn(
    const ushort_t* __restrict__ zb, const int* __restrict__ src,
    const int* __restrict__ dst, const float* __restrict__ w,
    float* __restrict__ ew2)
{
    const int t = blockIdx.x * 256 + threadIdx.x;
    const int e = t >> 3;
    if (e >= Ee) return;
    const int sub = t & 7;
    const int s = src[e];
    const int d = dst[e];
    const uint4 a  = ((const uint4*)(zb + (size_t)s * Hd))[sub];
    const uint4 bq = ((const uint4*)(zb + (size_t)d * Hd))[sub];
    float d12 = 0.f, d11 = 0.f, d22 = 0.f;
    dot2(a.x, bq.x, d12, d11, d22);
    dot2(a.y, bq.y, d12, d11, d22);
    dot2(a.z, bq.z, d12, d11, d22);
    dot2(a.w, bq.w, d12, d11, d22);
    #pragma unroll
    for (int mm = 1; mm < 8; mm <<= 1) {
        d12 += __shfl_xor(d12, mm);
        d11 += __shfl_xor(d11, mm);
        d22 += __shfl_xor(d22, mm);
    }
    if (sub == 0) {
        const float n1 = fmaxf(sqrtf(d11), 1e-8f);
        const float n2 = fmaxf(sqrtf(d22), 1e-8f);
        ew2[e] = w[e] * (d12 / (n1 * n2));
    }
}

// ---------------- out = A @ W_out + b_out  [N,64]@[64,40] --------------------
__global__ __launch_bounds__(256) void k_gemm_out(
    const float* __restrict__ A, const float* __restrict__ W,
    const float* __restrict__ b, float* __restrict__ out)
{
    const int idx = blockIdx.x * 256 + threadIdx.x;
    if (idx >= Nn * OUTd) return;
    const int row = idx / OUTd;
    const int col = idx - row * OUTd;
    const float* ar = A + (size_t)row * Hd;
    float acc = b[col];
    #pragma unroll 8
    for (int k = 0; k < Hd; ++k) acc += ar[k] * W[k * OUTd + col];
    out[idx] = acc;
}

extern "C" void kernel_launch(void* const* d_in, const int* in_sizes, int n_in,
                              void* d_out, int out_size, void* d_ws, size_t ws_size,
                              hipStream_t stream)
{
    const float* x     = (const float*)d_in[0];
    const int*   src   = (const int*)d_in[1];
    const int*   dstI  = (const int*)d_in[2];
    const float* ew    = (const float*)d_in[3];
    const float* W_in  = (const float*)d_in[4];
    const float* b_in  = (const float*)d_in[5];
    const float* Ws    = (const float*)d_in[6];
    const float* bs    = (const float*)d_in[7];
    const float* temp  = (const float*)d_in[8];
    const float* We1   = (const float*)d_in[9];
    const float* be1   = (const float*)d_in[10];
    const float* We2   = (const float*)d_in[11];
    const float* be2   = (const float*)d_in[12];
    const float* W_out = (const float*)d_in[13];
    const float* b_out = (const float*)d_in[14];
    float* out = (float*)d_out;

    const size_t NH = (size_t)Nn * Hd;      // 3.2M
    float* ws      = (float*)d_ws;
    float* h       = ws;                    // [N,H] f32
    float* hidden  = ws + NH;               // [N,H] f32
    float* cur     = ws + 2 * NH;           // [N,H] f32 (also MLP intermediate)
    ushort_t* mb   = (ushort_t*)(ws + 3 * NH);  // [N,H] bf16 (m table / z table)
    float* ew2     = ws + 3 * NH + NH / 2;  // [E]
    int2* ep       = (int2*)(ew2 + Ee);     // [E] {src, w_bits}
    int* eid       = (int*)(ep + Ee);       // [E]
    int* counts    = eid + Ee;              // [N] (counts then cursor)
    int* rowptr    = counts + Nn;           // [N+1]

    const dim3 b256(256);
    const int gE  = (Ee + 255) / 256;       // 3125
    const int gR  = Nn / 16;                // 3125
    const int gW  = (Nn * 64) / 256;        // 12500

    // ---- CSR build (pass-1 weights packed directly) ----
    hipMemsetAsync(counts, 0, Nn * sizeof(int), stream);
    k_count<<<gE, b256, 0, stream>>>(dstI, counts);
    k_scan<<<1, 1024, 0, stream>>>(counts, rowptr);
    k_copy_int<<<(Nn + 255) / 256, b256, 0, stream>>>(rowptr, counts);
    k_fill<<<gE, b256, 0, stream>>>(src, dstI, ew, counts, ep, eid);

    k_gemm_in<<<gR, b256, 0, stream>>>(x, W_in, b_in, h);

    // ---- GPR pass 1 ----
    {
        const float* curin = h;
        for (int i = 0; i < Ll; ++i) {
            k_gemm64<<<gR, b256, 0, stream>>>(curin, Ws + (size_t)i * Hd * Hd,
                                              bs + (size_t)i * Hd, nullptr, mb, 2);
            k_gather<<<gW, b256, 0, stream>>>(mb, rowptr, ep, h, cur, hidden,
                                              temp, i + 1);
            curin = cur;
        }
    }

    // ---- edge attention ----
    k_gemm64<<<gR, b256, 0, stream>>>(hidden, We1, be1, cur, nullptr, 1);
    k_gemm64<<<gR, b256, 0, stream>>>(cur, We2, be2, nullptr, mb, 2);   // z bf16
    k_edge_attn<<<(Ee * 8) / 256, b256, 0, stream>>>(mb, src, dstI, ew, ew2);
    k_repack<<<gE, b256, 0, stream>>>(ew2, eid, ep);

    // ---- GPR pass 2 ----
    {
        const float* curin = h;
        for (int i = 0; i < Ll; ++i) {
            k_gemm64<<<gR, b256, 0, stream>>>(curin, Ws + (size_t)i * Hd * Hd,
                                              bs + (size_t)i * Hd, nullptr, mb, 2);
            k_gather<<<gW, b256, 0, stream>>>(mb, rowptr, ep, h, cur, hidden,
                                              temp, i + 1);
            curin = cur;
        }
    }

    k_gemm_out<<<(Nn * OUTd + 255) / 256, b256, 0, stream>>>(hidden, W_out, b_out, out);
}

// Round 5
// 1013.978 us; speedup vs baseline: 5.9065x; 1.0855x over previous
//
#include <hip/hip_runtime.h>

#define Nn 50000
#define Ee 800000
#define INd 512
#define Hd 64
#define OUTd 40
#define Ll 4
#define NSETS 7168   // total hi fragment-slots; lo mirror at +NSETS

typedef unsigned int uint;
typedef unsigned short ushort_t;
typedef __attribute__((ext_vector_type(8))) short bf16x8;
typedef __attribute__((ext_vector_type(4))) float f32x4;

__device__ __forceinline__ float bf2f(ushort_t u) {
    return __uint_as_float(((uint)u) << 16);
}
__device__ __forceinline__ ushort_t f2bf(float f) {
    uint u = __float_as_uint(f);
    return (ushort_t)((u + 0x7fffu + ((u >> 16) & 1u)) >> 16);   // RNE
}
__device__ __forceinline__ uint cvtpk(float a, float b) {
    uint r;
    asm("v_cvt_pk_bf16_f32 %0, %1, %2" : "=v"(r) : "v"(a), "v"(b));
    return r;                                  // lo=bf16(a), hi=bf16(b)
}
// pack 8 consecutive f32 into hi/lo split-bf16 fragments (hi+lo ≈ f32)
__device__ __forceinline__ void pack_split(const float4 fa, const float4 fb,
                                           bf16x8& hi, bf16x8& lo)
{
    union { bf16x8 v; uint u[4]; } H, L;
    H.u[0] = cvtpk(fa.x, fa.y);
    H.u[1] = cvtpk(fa.z, fa.w);
    H.u[2] = cvtpk(fb.x, fb.y);
    H.u[3] = cvtpk(fb.z, fb.w);
    L.u[0] = cvtpk(fa.x - __uint_as_float(H.u[0] << 16),
                   fa.y - __uint_as_float(H.u[0] & 0xffff0000u));
    L.u[1] = cvtpk(fa.z - __uint_as_float(H.u[1] << 16),
                   fa.w - __uint_as_float(H.u[1] & 0xffff0000u));
    L.u[2] = cvtpk(fb.x - __uint_as_float(H.u[2] << 16),
                   fb.y - __uint_as_float(H.u[2] & 0xffff0000u));
    L.u[3] = cvtpk(fb.z - __uint_as_float(H.u[3] << 16),
                   fb.w - __uint_as_float(H.u[3] & 0xffff0000u));
    hi = H.v; lo = L.v;
}

// ---------------- weight repack into MFMA B-fragment order (hi + lo) ---------
// idx = weight_base + (s*4+t)*64 + l; elem j = W[s*32 + (l>>4)*8 + j][t*16 + (l&15)]
// hi at o[idx*8], lo at o[(NSETS+idx)*8].
__global__ __launch_bounds__(256) void k_prep_all(
    const float* __restrict__ W_in, const float* __restrict__ Ws,
    const float* __restrict__ We1, const float* __restrict__ We2,
    ushort_t* __restrict__ o)
{
    const int idx = blockIdx.x * 256 + threadIdx.x;
    const float* W;
    int local;
    if (idx < 4096)      { W = W_in; local = idx; }
    else if (idx < 6144) { int q = idx - 4096; W = Ws + (size_t)(q >> 9) * 4096; local = q & 511; }
    else if (idx < 6656) { W = We1; local = idx - 6144; }
    else if (idx < NSETS){ W = We2; local = idx - 6656; }
    else return;
    const int l = local & 63, t = (local >> 6) & 3, s = local >> 8;
    const int kbase = (s << 5) + ((l >> 4) << 3);
    const int col = (t << 4) + (l & 15);
    ushort_t* oph = o + (size_t)idx * 8;
    ushort_t* opl = o + (size_t)(NSETS + idx) * 8;
    #pragma unroll
    for (int j = 0; j < 8; ++j) {
        const float v = W[(size_t)(kbase + j) * Hd + col];
        const ushort_t hbits = f2bf(v);
        oph[j] = hbits;
        opl[j] = f2bf(v - bf2f(hbits));
    }
}

// ---------------- input GEMM (MFMA): hb = bf16(x@W_in + b), hidden = v*temp0 -
__global__ __launch_bounds__(256) void k_gemm_in_mfma(
    const float* __restrict__ x, const ushort_t* __restrict__ Wb,
    const float* __restrict__ bias, const float* __restrict__ temp,
    ushort_t* __restrict__ hb, float* __restrict__ hidden)
{
    const int tid = threadIdx.x;
    const int l = tid & 63;
    const int lr = l & 15, lg = l >> 4;
    const int row0 = blockIdx.x * 64 + (tid >> 6) * 16;
    int arow = row0 + lr; if (arow >= Nn) arow = Nn - 1;
    const float* xp = x + (size_t)arow * INd + lg * 8;
    f32x4 acc[4];
    #pragma unroll
    for (int t = 0; t < 4; ++t) acc[t] = (f32x4){0.f, 0.f, 0.f, 0.f};
    #pragma unroll 4
    for (int s = 0; s < 16; ++s) {
        const float4 f0 = *(const float4*)(xp + s * 32);
        const float4 f1 = *(const float4*)(xp + s * 32 + 4);
        union { bf16x8 v; uint u[4]; } au;
        au.u[0] = cvtpk(f0.x, f0.y); au.u[1] = cvtpk(f0.z, f0.w);
        au.u[2] = cvtpk(f1.x, f1.y); au.u[3] = cvtpk(f1.z, f1.w);
        #pragma unroll
        for (int t = 0; t < 4; ++t) {
            const bf16x8 bfr = *(const bf16x8*)(Wb + ((size_t)(s * 4 + t) * 64 + l) * 8);
            acc[t] = __builtin_amdgcn_mfma_f32_16x16x32_bf16(au.v, bfr, acc[t], 0, 0, 0);
        }
    }
    const float t0 = temp[0];
    #pragma unroll
    for (int t = 0; t < 4; ++t) {
        const int col = t * 16 + lr;
        const float bc = bias[col];
        #pragma unroll
        for (int r = 0; r < 4; ++r) {
            const int row = row0 + lg * 4 + r;
            if (row >= Nn) continue;
            const float v = acc[t][r] + bc;
            hb[(size_t)row * Hd + col] = f2bf(v);
            hidden[(size_t)row * Hd + col] = v * t0;
        }
    }
}

// ---------------- 64x64 MFMA GEMM, split-bf16 (~f32 accurate), fused epilogue -
// v = Af@W + (sw ? sw[row]*bias : bias); opt relu; opt hidden += temp[tidx]*v;
// store to outf (f32) or outb (bf16).
__global__ __launch_bounds__(256) void k_mm64(
    const float* __restrict__ Af, const ushort_t* __restrict__ Wb,
    const float* __restrict__ bias, const float* __restrict__ sw,
    const float* __restrict__ temp, int tidx, float* __restrict__ hidden,
    float* __restrict__ outf, ushort_t* __restrict__ outb, int relu)
{
    const int tid = threadIdx.x;
    const int l = tid & 63;
    const int lr = l & 15, lg = l >> 4;
    const int row0 = blockIdx.x * 64 + (tid >> 6) * 16;
    int arow = row0 + lr; if (arow >= Nn) arow = Nn - 1;
    const float* ap = Af + (size_t)arow * Hd + lg * 8;
    bf16x8 ahi0, alo0, ahi1, alo1;
    pack_split(*(const float4*)(ap),      *(const float4*)(ap + 4),  ahi0, alo0);
    pack_split(*(const float4*)(ap + 32), *(const float4*)(ap + 36), ahi1, alo1);
    f32x4 acc[4];
    #pragma unroll
    for (int t = 0; t < 4; ++t) acc[t] = (f32x4){0.f, 0.f, 0.f, 0.f};
    #pragma unroll
    for (int s = 0; s < 2; ++s) {
        const bf16x8 ah = s ? ahi1 : ahi0;
        const bf16x8 al = s ? alo1 : alo0;
        #pragma unroll
        for (int t = 0; t < 4; ++t) {
            const size_t fo = ((size_t)(s * 4 + t) * 64 + l) * 8;
            const bf16x8 bh = *(const bf16x8*)(Wb + fo);
            const bf16x8 bl = *(const bf16x8*)(Wb + fo + (size_t)NSETS * 8);
            acc[t] = __builtin_amdgcn_mfma_f32_16x16x32_bf16(ah, bh, acc[t], 0, 0, 0);
            acc[t] = __builtin_amdgcn_mfma_f32_16x16x32_bf16(al, bh, acc[t], 0, 0, 0);
            acc[t] = __builtin_amdgcn_mfma_f32_16x16x32_bf16(ah, bl, acc[t], 0, 0, 0);
        }
    }
    const float tk = temp ? temp[tidx] : 0.0f;
    float swv[4];
    if (sw) {
        #pragma unroll
        for (int r = 0; r < 4; ++r) {
            const int row = row0 + lg * 4 + r;
            swv[r] = (row < Nn) ? sw[row] : 0.f;
        }
    }
    #pragma unroll
    for (int t = 0; t < 4; ++t) {
        const int col = t * 16 + lr;
        const float bc = bias[col];
        #pragma unroll
        for (int r = 0; r < 4; ++r) {
            const int row = row0 + lg * 4 + r;
            if (row >= Nn) continue;
            float v = acc[t][r] + (sw ? swv[r] * bc : bc);
            if (relu) v = fmaxf(v, 0.f);
            if (hidden) hidden[(size_t)row * Hd + col] += tk * v;
            if (outf) outf[(size_t)row * Hd + col] = v;
            else      outb[(size_t)row * Hd + col] = f2bf(v);
        }
    }
}

// ---------------- CSR build --------------------------------------------------
__global__ __launch_bounds__(256) void k_count(
    const int* __restrict__ dst, int* __restrict__ counts)
{
    const int e = blockIdx.x * 256 + threadIdx.x;
    if (e < Ee) atomicAdd(&counts[dst[e]], 1);
}

__global__ __launch_bounds__(1024) void k_scan(
    const int* __restrict__ counts, int* __restrict__ rowptr)
{
    __shared__ int sdata[1024];
    const int t = threadIdx.x;
    const int chunk = (Nn + 1023) / 1024;
    const int beg = t * chunk;
    const int end = min(Nn, beg + chunk);
    int s = 0;
    for (int i = beg; i < end; ++i) s += counts[i];
    sdata[t] = s;
    __syncthreads();
    for (int off = 1; off < 1024; off <<= 1) {
        int v = sdata[t];
        int u = (t >= off) ? sdata[t - off] : 0;
        __syncthreads();
        sdata[t] = v + u;
        __syncthreads();
    }
    int run = sdata[t] - s;
    for (int i = beg; i < end; ++i) {
        rowptr[i] = run;
        run += counts[i];
    }
    if (t == 0) rowptr[Nn] = sdata[1023];
}

__global__ __launch_bounds__(256) void k_copy_int(
    const int* __restrict__ a, int* __restrict__ b)
{
    const int i = blockIdx.x * 256 + threadIdx.x;
    if (i < Nn) b[i] = a[i];
}

__global__ __launch_bounds__(256) void k_fill(
    const int* __restrict__ src, const int* __restrict__ dst,
    const float* __restrict__ w, int* __restrict__ cursor,
    int2* __restrict__ ep, int* __restrict__ eid)
{
    const int e = blockIdx.x * 256 + threadIdx.x;
    if (e >= Ee) return;
    const int d = dst[e];
    const int slot = atomicAdd(&cursor[d], 1);
    ep[slot] = make_int2(src[e], __float_as_int(w[e]));
    eid[slot] = e;
}

__global__ __launch_bounds__(256) void k_repack(
    const float* __restrict__ w2, const int* __restrict__ eid,
    int2* __restrict__ ep)
{
    const int i = blockIdx.x * 256 + threadIdx.x;
    if (i < Ee) ep[i].y = __float_as_int(w2[eid[i]]);
}

// ---------------- pull gather: aggf = sum w*tb[src] (f32), sw = sum w --------
__global__ __launch_bounds__(256) void k_gather_agg(
    const ushort_t* __restrict__ tb, const int* __restrict__ rowptr,
    const int2* __restrict__ ep, float* __restrict__ aggf,
    float* __restrict__ sw)
{
    const int node = (blockIdx.x * 256 + threadIdx.x) >> 6;
    const int lane = threadIdx.x & 63;
    if (node >= Nn) return;
    const int beg = rowptr[node], end = rowptr[node + 1];
    float acc = 0.f, wsum = 0.f;
    for (int i = beg; i < end; ++i) {
        const int2 e = ep[i];
        const float wv = __int_as_float(e.y);
        acc += bf2f(tb[(size_t)e.x * Hd + lane]) * wv;
        wsum += wv;
    }
    aggf[(size_t)node * Hd + lane] = acc;
    if (lane == 0) sw[node] = wsum;
}

// ---------------- hidden = bf2f(hb) * temp[0]  (8 elems/thread) --------------
__global__ __launch_bounds__(256) void k_init_hidden2(
    const ushort_t* __restrict__ hb, float* __restrict__ hidden,
    const float* __restrict__ temp)
{
    const int i = blockIdx.x * 256 + threadIdx.x;
    if (i >= (Nn * Hd) / 8) return;             // 400000 (grid rounds up!)
    const float t0 = temp[0];
    const uint4 u = ((const uint4*)hb)[i];
    float4 o0, o1;
    o0.x = bf2f(u.x & 0xffff) * t0; o0.y = bf2f(u.x >> 16) * t0;
    o0.z = bf2f(u.y & 0xffff) * t0; o0.w = bf2f(u.y >> 16) * t0;
    o1.x = bf2f(u.z & 0xffff) * t0; o1.y = bf2f(u.z >> 16) * t0;
    o1.z = bf2f(u.w & 0xffff) * t0; o1.w = bf2f(u.w >> 16) * t0;
    ((float4*)hidden)[2 * i] = o0;
    ((float4*)hidden)[2 * i + 1] = o1;
}

// ---------------- edge attention on bf16 z: 8 threads/edge -------------------
__device__ __forceinline__ void dot2(uint ua, uint ub,
                                     float& d12, float& d11, float& d22)
{
    const float al = __uint_as_float(ua << 16);
    const float ah = __uint_as_float(ua & 0xffff0000u);
    const float bl = __uint_as_float(ub << 16);
    const float bh = __uint_as_float(ub & 0xffff0000u);
    d12 += al * bl + ah * bh;
    d11 += al * al + ah * ah;
    d22 += bl * bl + bh * bh;
}

__global__ __launch_bounds__(256) void k_edge_attn(
    const ushort_t* __restrict__ zb, const int* __restrict__ src,
    const int* __restrict__ dst, const float* __restrict__ w,
    float* __restrict__ ew2)
{
    const int t = blockIdx.x * 256 + threadIdx.x;
    const int e = t >> 3;
    if (e >= Ee) return;
    const int sub = t & 7;
    const int s = src[e];
    const int d = dst[e];
    const uint4 a  = ((const uint4*)(zb + (size_t)s * Hd))[sub];
    const uint4 bq = ((const uint4*)(zb + (size_t)d * Hd))[sub];
    float d12 = 0.f, d11 = 0.f, d22 = 0.f;
    dot2(a.x, bq.x, d12, d11, d22);
    dot2(a.y, bq.y, d12, d11, d22);
    dot2(a.z, bq.z, d12, d11, d22);
    dot2(a.w, bq.w, d12, d11, d22);
    #pragma unroll
    for (int mm = 1; mm < 8; mm <<= 1) {
        d12 += __shfl_xor(d12, mm);
        d11 += __shfl_xor(d11, mm);
        d22 += __shfl_xor(d22, mm);
    }
    if (sub == 0) {
        const float n1 = fmaxf(sqrtf(d11), 1e-8f);
        const float n2 = fmaxf(sqrtf(d22), 1e-8f);
        ew2[e] = w[e] * (d12 / (n1 * n2));
    }
}

// ---------------- out = hidden @ W_out + b_out  [N,64]@[64,40] ---------------
__global__ __launch_bounds__(256) void k_gemm_out(
    const float* __restrict__ A, const float* __restrict__ W,
    const float* __restrict__ b, float* __restrict__ out)
{
    const int idx = blockIdx.x * 256 + threadIdx.x;
    if (idx >= Nn * OUTd) return;
    const int row = idx / OUTd;
    const int col = idx - row * OUTd;
    const float* ar = A + (size_t)row * Hd;
    float acc = b[col];
    #pragma unroll 8
    for (int k = 0; k < Hd; ++k) acc += ar[k] * W[k * OUTd + col];
    out[idx] = acc;
}

extern "C" void kernel_launch(void* const* d_in, const int* in_sizes, int n_in,
                              void* d_out, int out_size, void* d_ws, size_t ws_size,
                              hipStream_t stream)
{
    const float* x     = (const float*)d_in[0];
    const int*   src   = (const int*)d_in[1];
    const int*   dstI  = (const int*)d_in[2];
    const float* ew    = (const float*)d_in[3];
    const float* W_in  = (const float*)d_in[4];
    const float* b_in  = (const float*)d_in[5];
    const float* Ws    = (const float*)d_in[6];
    const float* bs    = (const float*)d_in[7];
    const float* temp  = (const float*)d_in[8];
    const float* We1   = (const float*)d_in[9];
    const float* be1   = (const float*)d_in[10];
    const float* We2   = (const float*)d_in[11];
    const float* be2   = (const float*)d_in[12];
    const float* W_out = (const float*)d_in[13];
    const float* b_out = (const float*)d_in[14];
    float* out = (float*)d_out;

    const size_t NH = (size_t)Nn * Hd;           // 3.2M
    float* ws_f     = (float*)d_ws;
    float* hidden   = ws_f;                      // [N,H] f32
    float* aggf     = ws_f + NH;                 // [N,H] f32
    ushort_t* hb    = (ushort_t*)(ws_f + 2 * NH);// [N,H] bf16
    ushort_t* curb  = hb + NH;                   // [N,H] bf16
    float* sw       = (float*)(curb + NH);       // [N]
    float* ew2      = sw + Nn;                   // [E]
    int2* ep        = (int2*)(ew2 + Ee);         // [E]
    int* eid        = (int*)(ep + Ee);           // [E]
    int* counts     = eid + Ee;                  // [N]
    int* rowptr     = counts + Nn;               // [N+1]
    uintptr_t wp    = ((uintptr_t)(rowptr + Nn + 1) + 15) & ~(uintptr_t)15;
    ushort_t* wb    = (ushort_t*)wp;             // 2*NSETS*8 bf16
    ushort_t* Wbin  = wb;                        // hi lanesets 0..4095
    ushort_t* Wbs   = wb + (size_t)4096 * 8;     // Ws[i] at + i*512*8
    ushort_t* Wbe1  = wb + (size_t)6144 * 8;
    ushort_t* Wbe2  = wb + (size_t)6656 * 8;

    const dim3 b256(256);
    const int gE  = (Ee + 255) / 256;            // 3125
    const int gB  = (Nn + 63) / 64;              // 782
    const int gW  = (Nn * 64) / 256;             // 12500
    const int gI  = ((int)(NH / 8) + 255) / 256; // 1563

    // ---- CSR build + weight repack ----
    hipMemsetAsync(counts, 0, Nn * sizeof(int), stream);
    k_count<<<gE, b256, 0, stream>>>(dstI, counts);
    k_scan<<<1, 1024, 0, stream>>>(counts, rowptr);
    k_copy_int<<<(Nn + 255) / 256, b256, 0, stream>>>(rowptr, counts);
    k_fill<<<gE, b256, 0, stream>>>(src, dstI, ew, counts, ep, eid);
    k_prep_all<<<28, b256, 0, stream>>>(W_in, Ws, We1, We2, wb);

    // ---- input projection + pass-1 hidden init ----
    k_gemm_in_mfma<<<gB, b256, 0, stream>>>(x, Wbin, b_in, temp, hb, hidden);

    // ---- GPR pass 1 ----
    {
        const ushort_t* tbl = hb;
        for (int i = 0; i < Ll; ++i) {
            k_gather_agg<<<gW, b256, 0, stream>>>(tbl, rowptr, ep, aggf, sw);
            k_mm64<<<gB, b256, 0, stream>>>(aggf, Wbs + (size_t)i * 512 * 8,
                                            bs + (size_t)i * Hd, sw, temp, i + 1,
                                            hidden, nullptr, curb, 1);
            tbl = curb;
        }
    }

    // ---- edge attention ----
    k_mm64<<<gB, b256, 0, stream>>>(hidden, Wbe1, be1, nullptr, nullptr, 0,
                                    nullptr, aggf, nullptr, 1);      // relu MLP1 (f32)
    k_mm64<<<gB, b256, 0, stream>>>(aggf, Wbe2, be2, nullptr, nullptr, 0,
                                    nullptr, nullptr, curb, 0);      // z (bf16)
    k_edge_attn<<<(Ee * 8) / 256, b256, 0, stream>>>(curb, src, dstI, ew, ew2);
    k_repack<<<gE, b256, 0, stream>>>(ew2, eid, ep);

    // ---- GPR pass 2 ----
    k_init_hidden2<<<gI, b256, 0, stream>>>(hb, hidden, temp);
    {
        const ushort_t* tbl = hb;
        for (int i = 0; i < Ll; ++i) {
            k_gather_agg<<<gW, b256, 0, stream>>>(tbl, rowptr, ep, aggf, sw);
            k_mm64<<<gB, b256, 0, stream>>>(aggf, Wbs + (size_t)i * 512 * 8,
                                            bs + (size_t)i * Hd, sw, temp, i + 1,
                                            hidden, nullptr, curb, 1);
            tbl = curb;
        }
    }

    k_gemm_out<<<(Nn * OUTd + 255) / 256, b256, 0, stream>>>(hidden, W_out, b_out, out);
}

// Round 6
// 577.403 us; speedup vs baseline: 10.3723x; 1.7561x over previous
//
#include <hip/hip_runtime.h>

#define Nn 50000
#define Ee 800000
#define INd 512
#define Hd 64
#define OUTd 40
#define Ll 4
#define NSETS 7168   // total hi fragment-slots; lo mirror at +NSETS
#define SCAN_B 196   // ceil(Nn/256)

typedef unsigned int uint;
typedef unsigned short ushort_t;
typedef __attribute__((ext_vector_type(8))) short bf16x8;
typedef __attribute__((ext_vector_type(4))) float f32x4;

__device__ __forceinline__ float bf2f(ushort_t u) {
    return __uint_as_float(((uint)u) << 16);
}
__device__ __forceinline__ ushort_t f2bf(float f) {
    uint u = __float_as_uint(f);
    return (ushort_t)((u + 0x7fffu + ((u >> 16) & 1u)) >> 16);   // RNE
}
__device__ __forceinline__ uint cvtpk(float a, float b) {
    uint r;
    asm("v_cvt_pk_bf16_f32 %0, %1, %2" : "=v"(r) : "v"(a), "v"(b));
    return r;                                  // lo=bf16(a), hi=bf16(b)
}
// pack 8 consecutive f32 into hi/lo split-bf16 fragments (hi+lo ≈ f32)
__device__ __forceinline__ void pack_split(const float4 fa, const float4 fb,
                                           bf16x8& hi, bf16x8& lo)
{
    union { bf16x8 v; uint u[4]; } H, L;
    H.u[0] = cvtpk(fa.x, fa.y);
    H.u[1] = cvtpk(fa.z, fa.w);
    H.u[2] = cvtpk(fb.x, fb.y);
    H.u[3] = cvtpk(fb.z, fb.w);
    L.u[0] = cvtpk(fa.x - __uint_as_float(H.u[0] << 16),
                   fa.y - __uint_as_float(H.u[0] & 0xffff0000u));
    L.u[1] = cvtpk(fa.z - __uint_as_float(H.u[1] << 16),
                   fa.w - __uint_as_float(H.u[1] & 0xffff0000u));
    L.u[2] = cvtpk(fb.x - __uint_as_float(H.u[2] << 16),
                   fb.y - __uint_as_float(H.u[2] & 0xffff0000u));
    L.u[3] = cvtpk(fb.z - __uint_as_float(H.u[3] << 16),
                   fb.w - __uint_as_float(H.u[3] & 0xffff0000u));
    hi = H.v; lo = L.v;
}

// ---------------- weight repack into MFMA B-fragment order (hi + lo) ---------
__global__ __launch_bounds__(256) void k_prep_all(
    const float* __restrict__ W_in, const float* __restrict__ Ws,
    const float* __restrict__ We1, const float* __restrict__ We2,
    ushort_t* __restrict__ o)
{
    const int idx = blockIdx.x * 256 + threadIdx.x;
    const float* W;
    int local;
    if (idx < 4096)      { W = W_in; local = idx; }
    else if (idx < 6144) { int q = idx - 4096; W = Ws + (size_t)(q >> 9) * 4096; local = q & 511; }
    else if (idx < 6656) { W = We1; local = idx - 6144; }
    else if (idx < NSETS){ W = We2; local = idx - 6656; }
    else return;
    const int l = local & 63, t = (local >> 6) & 3, s = local >> 8;
    const int kbase = (s << 5) + ((l >> 4) << 3);
    const int col = (t << 4) + (l & 15);
    ushort_t* oph = o + (size_t)idx * 8;
    ushort_t* opl = o + (size_t)(NSETS + idx) * 8;
    #pragma unroll
    for (int j = 0; j < 8; ++j) {
        const float v = W[(size_t)(kbase + j) * Hd + col];
        const ushort_t hbits = f2bf(v);
        oph[j] = hbits;
        opl[j] = f2bf(v - bf2f(hbits));
    }
}

// ---------------- input GEMM (MFMA): hb = bf16(x@W_in + b), hidden = v*temp0 -
__global__ __launch_bounds__(256) void k_gemm_in_mfma(
    const float* __restrict__ x, const ushort_t* __restrict__ Wb,
    const float* __restrict__ bias, const float* __restrict__ temp,
    ushort_t* __restrict__ hb, float* __restrict__ hidden)
{
    const int tid = threadIdx.x;
    const int l = tid & 63;
    const int lr = l & 15, lg = l >> 4;
    const int row0 = blockIdx.x * 64 + (tid >> 6) * 16;
    int arow = row0 + lr; if (arow >= Nn) arow = Nn - 1;
    const float* xp = x + (size_t)arow * INd + lg * 8;
    f32x4 acc[4];
    #pragma unroll
    for (int t = 0; t < 4; ++t) acc[t] = (f32x4){0.f, 0.f, 0.f, 0.f};
    #pragma unroll 4
    for (int s = 0; s < 16; ++s) {
        const float4 f0 = *(const float4*)(xp + s * 32);
        const float4 f1 = *(const float4*)(xp + s * 32 + 4);
        union { bf16x8 v; uint u[4]; } au;
        au.u[0] = cvtpk(f0.x, f0.y); au.u[1] = cvtpk(f0.z, f0.w);
        au.u[2] = cvtpk(f1.x, f1.y); au.u[3] = cvtpk(f1.z, f1.w);
        #pragma unroll
        for (int t = 0; t < 4; ++t) {
            const bf16x8 bfr = *(const bf16x8*)(Wb + ((size_t)(s * 4 + t) * 64 + l) * 8);
            acc[t] = __builtin_amdgcn_mfma_f32_16x16x32_bf16(au.v, bfr, acc[t], 0, 0, 0);
        }
    }
    const float t0 = temp[0];
    #pragma unroll
    for (int t = 0; t < 4; ++t) {
        const int col = t * 16 + lr;
        const float bc = bias[col];
        #pragma unroll
        for (int r = 0; r < 4; ++r) {
            const int row = row0 + lg * 4 + r;
            if (row >= Nn) continue;
            const float v = acc[t][r] + bc;
            hb[(size_t)row * Hd + col] = f2bf(v);
            hidden[(size_t)row * Hd + col] = v * t0;
        }
    }
}

// ---------------- 64x64 MFMA GEMM, split-bf16, fused epilogue ----------------
__global__ __launch_bounds__(256) void k_mm64(
    const float* __restrict__ Af, const ushort_t* __restrict__ Wb,
    const float* __restrict__ bias, const float* __restrict__ sw,
    const float* __restrict__ temp, int tidx, float* __restrict__ hidden,
    float* __restrict__ outf, ushort_t* __restrict__ outb, int relu)
{
    const int tid = threadIdx.x;
    const int l = tid & 63;
    const int lr = l & 15, lg = l >> 4;
    const int row0 = blockIdx.x * 64 + (tid >> 6) * 16;
    int arow = row0 + lr; if (arow >= Nn) arow = Nn - 1;
    const float* ap = Af + (size_t)arow * Hd + lg * 8;
    bf16x8 ahi0, alo0, ahi1, alo1;
    pack_split(*(const float4*)(ap),      *(const float4*)(ap + 4),  ahi0, alo0);
    pack_split(*(const float4*)(ap + 32), *(const float4*)(ap + 36), ahi1, alo1);
    f32x4 acc[4];
    #pragma unroll
    for (int t = 0; t < 4; ++t) acc[t] = (f32x4){0.f, 0.f, 0.f, 0.f};
    #pragma unroll
    for (int s = 0; s < 2; ++s) {
        const bf16x8 ah = s ? ahi1 : ahi0;
        const bf16x8 al = s ? alo1 : alo0;
        #pragma unroll
        for (int t = 0; t < 4; ++t) {
            const size_t fo = ((size_t)(s * 4 + t) * 64 + l) * 8;
            const bf16x8 bh = *(const bf16x8*)(Wb + fo);
            const bf16x8 bl = *(const bf16x8*)(Wb + fo + (size_t)NSETS * 8);
            acc[t] = __builtin_amdgcn_mfma_f32_16x16x32_bf16(ah, bh, acc[t], 0, 0, 0);
            acc[t] = __builtin_amdgcn_mfma_f32_16x16x32_bf16(al, bh, acc[t], 0, 0, 0);
            acc[t] = __builtin_amdgcn_mfma_f32_16x16x32_bf16(ah, bl, acc[t], 0, 0, 0);
        }
    }
    const float tk = temp ? temp[tidx] : 0.0f;
    float swv[4];
    if (sw) {
        #pragma unroll
        for (int r = 0; r < 4; ++r) {
            const int row = row0 + lg * 4 + r;
            swv[r] = (row < Nn) ? sw[row] : 0.f;
        }
    }
    #pragma unroll
    for (int t = 0; t < 4; ++t) {
        const int col = t * 16 + lr;
        const float bc = bias[col];
        #pragma unroll
        for (int r = 0; r < 4; ++r) {
            const int row = row0 + lg * 4 + r;
            if (row >= Nn) continue;
            float v = acc[t][r] + (sw ? swv[r] * bc : bc);
            if (relu) v = fmaxf(v, 0.f);
            if (hidden) hidden[(size_t)row * Hd + col] += tk * v;
            if (outf) outf[(size_t)row * Hd + col] = v;
            else      outb[(size_t)row * Hd + col] = f2bf(v);
        }
    }
}

// ---------------- CSR build --------------------------------------------------
__global__ __launch_bounds__(256) void k_count(
    const int* __restrict__ dst, int* __restrict__ counts)
{
    const int e = blockIdx.x * 256 + threadIdx.x;
    if (e < Ee) atomicAdd(&counts[dst[e]], 1);
}

// per-block sums of counts (coalesced)
__global__ __launch_bounds__(256) void k_bsum(
    const int* __restrict__ counts, int* __restrict__ bsum)
{
    __shared__ int sd[256];
    const int t = threadIdx.x;
    const int i = blockIdx.x * 256 + t;
    sd[t] = (i < Nn) ? counts[i] : 0;
    __syncthreads();
    #pragma unroll
    for (int off = 128; off > 0; off >>= 1) {
        if (t < off) sd[t] += sd[t + off];
        __syncthreads();
    }
    if (t == 0) bsum[blockIdx.x] = sd[0];
}

// 1-block exclusive scan of bsum[SCAN_B] -> boff; rowptr[Nn] = total
__global__ __launch_bounds__(256) void k_scan_b(
    const int* __restrict__ bsum, int* __restrict__ boff,
    int* __restrict__ rowptr)
{
    __shared__ int sd[256];
    const int t = threadIdx.x;
    const int v = (t < SCAN_B) ? bsum[t] : 0;
    sd[t] = v;
    __syncthreads();
    #pragma unroll
    for (int off = 1; off < 256; off <<= 1) {
        const int u = (t >= off) ? sd[t - off] : 0;
        __syncthreads();
        sd[t] += u;
        __syncthreads();
    }
    if (t < SCAN_B) boff[t] = sd[t] - v;     // exclusive block offset
    if (t == 255) rowptr[Nn] = sd[255];
}

// block-local exclusive scan + block offset -> rowptr[i]; cursor[i] = rowptr[i]
__global__ __launch_bounds__(256) void k_emit(
    const int* __restrict__ counts, const int* __restrict__ boff,
    int* __restrict__ rowptr, int* __restrict__ cursor)
{
    __shared__ int sd[256];
    const int t = threadIdx.x;
    const int i = blockIdx.x * 256 + t;
    const int v = (i < Nn) ? counts[i] : 0;
    sd[t] = v;
    __syncthreads();
    #pragma unroll
    for (int off = 1; off < 256; off <<= 1) {
        const int u = (t >= off) ? sd[t - off] : 0;
        __syncthreads();
        sd[t] += u;
        __syncthreads();
    }
    if (i < Nn) {
        const int r = boff[blockIdx.x] + sd[t] - v;
        rowptr[i] = r;
        cursor[i] = r;
    }
}

__global__ __launch_bounds__(256) void k_fill(
    const int* __restrict__ src, const int* __restrict__ dst,
    const float* __restrict__ w, int* __restrict__ cursor,
    int2* __restrict__ ep, int* __restrict__ eid)
{
    const int e = blockIdx.x * 256 + threadIdx.x;
    if (e >= Ee) return;
    const int d = dst[e];
    const int slot = atomicAdd(&cursor[d], 1);
    ep[slot] = make_int2(src[e], __float_as_int(w[e]));
    eid[slot] = e;
}

__global__ __launch_bounds__(256) void k_repack(
    const float* __restrict__ w2, const int* __restrict__ eid,
    int2* __restrict__ ep)
{
    const int i = blockIdx.x * 256 + threadIdx.x;
    if (i < Ee) ep[i].y = __float_as_int(w2[eid[i]]);
}

// ---------------- pull gather: aggf = sum w*tb[src] (f32), sw = sum w --------
// wave = node; 2 half-waves process even/odd CSR slots; lane loads uint
// (2 bf16 features); unroll 4 -> 8 row-loads in flight per wave.
__global__ __launch_bounds__(256) void k_gather_agg(
    const ushort_t* __restrict__ tb, const int* __restrict__ rowptr,
    const int2* __restrict__ ep, float* __restrict__ aggf,
    float* __restrict__ sw)
{
    const int node = (blockIdx.x * 256 + threadIdx.x) >> 6;
    const int lane = threadIdx.x & 63;
    if (node >= Nn) return;
    const int beg = rowptr[node], end = rowptr[node + 1];
    const int half = lane >> 5;          // 0: even slots, 1: odd slots
    const int fp   = lane & 31;          // feature pair (2fp, 2fp+1)
    float a0 = 0.f, a1 = 0.f, wsum = 0.f;
    int i = beg + half;
    for (; i + 6 < end; i += 8) {
        const int2 e0 = ep[i];
        const int2 e1 = ep[i + 2];
        const int2 e2 = ep[i + 4];
        const int2 e3 = ep[i + 6];
        const uint r0 = *(const uint*)(tb + (size_t)e0.x * Hd + 2 * fp);
        const uint r1 = *(const uint*)(tb + (size_t)e1.x * Hd + 2 * fp);
        const uint r2 = *(const uint*)(tb + (size_t)e2.x * Hd + 2 * fp);
        const uint r3 = *(const uint*)(tb + (size_t)e3.x * Hd + 2 * fp);
        const float w0 = __int_as_float(e0.y), w1 = __int_as_float(e1.y);
        const float w2 = __int_as_float(e2.y), w3 = __int_as_float(e3.y);
        a0 += bf2f((ushort_t)(r0 & 0xffffu)) * w0 + bf2f((ushort_t)(r1 & 0xffffu)) * w1
            + bf2f((ushort_t)(r2 & 0xffffu)) * w2 + bf2f((ushort_t)(r3 & 0xffffu)) * w3;
        a1 += bf2f((ushort_t)(r0 >> 16)) * w0 + bf2f((ushort_t)(r1 >> 16)) * w1
            + bf2f((ushort_t)(r2 >> 16)) * w2 + bf2f((ushort_t)(r3 >> 16)) * w3;
        wsum += w0 + w1 + w2 + w3;
    }
    for (; i < end; i += 2) {
        const int2 e = ep[i];
        const uint r = *(const uint*)(tb + (size_t)e.x * Hd + 2 * fp);
        const float w = __int_as_float(e.y);
        a0 += bf2f((ushort_t)(r & 0xffffu)) * w;
        a1 += bf2f((ushort_t)(r >> 16)) * w;
        wsum += w;
    }
    // combine even/odd halves (lane fp gets lane fp+32's partials)
    a0 += __shfl(a0, fp + 32);
    a1 += __shfl(a1, fp + 32);
    wsum += __shfl(wsum, fp + 32);
    if (lane < 32) {
        float2 o; o.x = a0; o.y = a1;
        ((float2*)(aggf + (size_t)node * Hd))[fp] = o;
        if (lane == 0) sw[node] = wsum;
    }
}

// ---------------- hidden = bf2f(hb) * temp[0]  (8 elems/thread) --------------
__global__ __launch_bounds__(256) void k_init_hidden2(
    const ushort_t* __restrict__ hb, float* __restrict__ hidden,
    const float* __restrict__ temp)
{
    const int i = blockIdx.x * 256 + threadIdx.x;
    if (i >= (Nn * Hd) / 8) return;
    const float t0 = temp[0];
    const uint4 u = ((const uint4*)hb)[i];
    float4 o0, o1;
    o0.x = bf2f(u.x & 0xffff) * t0; o0.y = bf2f(u.x >> 16) * t0;
    o0.z = bf2f(u.y & 0xffff) * t0; o0.w = bf2f(u.y >> 16) * t0;
    o1.x = bf2f(u.z & 0xffff) * t0; o1.y = bf2f(u.z >> 16) * t0;
    o1.z = bf2f(u.w & 0xffff) * t0; o1.w = bf2f(u.w >> 16) * t0;
    ((float4*)hidden)[2 * i] = o0;
    ((float4*)hidden)[2 * i + 1] = o1;
}

// ---------------- edge attention on bf16 z: 8 threads/edge -------------------
__device__ __forceinline__ void dot2(uint ua, uint ub,
                                     float& d12, float& d11, float& d22)
{
    const float al = __uint_as_float(ua << 16);
    const float ah = __uint_as_float(ua & 0xffff0000u);
    const float bl = __uint_as_float(ub << 16);
    const float bh = __uint_as_float(ub & 0xffff0000u);
    d12 += al * bl + ah * bh;
    d11 += al * al + ah * ah;
    d22 += bl * bl + bh * bh;
}

__global__ __launch_bounds__(256) void k_edge_attn(
    const ushort_t* __restrict__ zb, const int* __restrict__ src,
    const int* __restrict__ dst, const float* __restrict__ w,
    float* __restrict__ ew2)
{
    const int t = blockIdx.x * 256 + threadIdx.x;
    const int e = t >> 3;
    if (e >= Ee) return;
    const int sub = t & 7;
    const int s = src[e];
    const int d = dst[e];
    const uint4 a  = ((const uint4*)(zb + (size_t)s * Hd))[sub];
    const uint4 bq = ((const uint4*)(zb + (size_t)d * Hd))[sub];
    float d12 = 0.f, d11 = 0.f, d22 = 0.f;
    dot2(a.x, bq.x, d12, d11, d22);
    dot2(a.y, bq.y, d12, d11, d22);
    dot2(a.z, bq.z, d12, d11, d22);
    dot2(a.w, bq.w, d12, d11, d22);
    #pragma unroll
    for (int mm = 1; mm < 8; mm <<= 1) {
        d12 += __shfl_xor(d12, mm);
        d11 += __shfl_xor(d11, mm);
        d22 += __shfl_xor(d22, mm);
    }
    if (sub == 0) {
        const float n1 = fmaxf(sqrtf(d11), 1e-8f);
        const float n2 = fmaxf(sqrtf(d22), 1e-8f);
        ew2[e] = w[e] * (d12 / (n1 * n2));
    }
}

// ---------------- out = hidden @ W_out + b_out  [N,64]@[64,40] ---------------
__global__ __launch_bounds__(256) void k_gemm_out(
    const float* __restrict__ A, const float* __restrict__ W,
    const float* __restrict__ b, float* __restrict__ out)
{
    const int idx = blockIdx.x * 256 + threadIdx.x;
    if (idx >= Nn * OUTd) return;
    const int row = idx / OUTd;
    const int col = idx - row * OUTd;
    const float* ar = A + (size_t)row * Hd;
    float acc = b[col];
    #pragma unroll 8
    for (int k = 0; k < Hd; ++k) acc += ar[k] * W[k * OUTd + col];
    out[idx] = acc;
}

extern "C" void kernel_launch(void* const* d_in, const int* in_sizes, int n_in,
                              void* d_out, int out_size, void* d_ws, size_t ws_size,
                              hipStream_t stream)
{
    const float* x     = (const float*)d_in[0];
    const int*   src   = (const int*)d_in[1];
    const int*   dstI  = (const int*)d_in[2];
    const float* ew    = (const float*)d_in[3];
    const float* W_in  = (const float*)d_in[4];
    const float* b_in  = (const float*)d_in[5];
    const float* Ws    = (const float*)d_in[6];
    const float* bs    = (const float*)d_in[7];
    const float* temp  = (const float*)d_in[8];
    const float* We1   = (const float*)d_in[9];
    const float* be1   = (const float*)d_in[10];
    const float* We2   = (const float*)d_in[11];
    const float* be2   = (const float*)d_in[12];
    const float* W_out = (const float*)d_in[13];
    const float* b_out = (const float*)d_in[14];
    float* out = (float*)d_out;

    const size_t NH = (size_t)Nn * Hd;           // 3.2M
    float* ws_f     = (float*)d_ws;
    float* hidden   = ws_f;                      // [N,H] f32
    float* aggf     = ws_f + NH;                 // [N,H] f32
    ushort_t* hb    = (ushort_t*)(ws_f + 2 * NH);// [N,H] bf16
    ushort_t* curb  = hb + NH;                   // [N,H] bf16
    float* sw       = (float*)(curb + NH);       // [N]
    float* ew2      = sw + Nn;                   // [E]
    int2* ep        = (int2*)(ew2 + Ee);         // [E]
    int* eid        = (int*)(ep + Ee);           // [E]
    int* counts     = eid + Ee;                  // [N]
    int* rowptr     = counts + Nn;               // [N+1]
    int* cursor     = rowptr + Nn + 1;           // [N]
    int* bsum       = cursor + Nn;               // [SCAN_B]
    int* boff       = bsum + SCAN_B;             // [SCAN_B]
    uintptr_t wp    = ((uintptr_t)(boff + SCAN_B) + 15) & ~(uintptr_t)15;
    ushort_t* wb    = (ushort_t*)wp;             // 2*NSETS*8 bf16
    ushort_t* Wbin  = wb;
    ushort_t* Wbs   = wb + (size_t)4096 * 8;
    ushort_t* Wbe1  = wb + (size_t)6144 * 8;
    ushort_t* Wbe2  = wb + (size_t)6656 * 8;

    const dim3 b256(256);
    const int gE  = (Ee + 255) / 256;            // 3125
    const int gB  = (Nn + 63) / 64;              // 782
    const int gW  = (Nn * 64) / 256;             // 12500
    const int gI  = ((int)(NH / 8) + 255) / 256; // 1563

    // ---- CSR build + weight repack ----
    hipMemsetAsync(counts, 0, Nn * sizeof(int), stream);
    k_count<<<gE, b256, 0, stream>>>(dstI, counts);
    k_bsum<<<SCAN_B, b256, 0, stream>>>(counts, bsum);
    k_scan_b<<<1, b256, 0, stream>>>(bsum, boff, rowptr);
    k_emit<<<SCAN_B, b256, 0, stream>>>(counts, boff, rowptr, cursor);
    k_fill<<<gE, b256, 0, stream>>>(src, dstI, ew, cursor, ep, eid);
    k_prep_all<<<28, b256, 0, stream>>>(W_in, Ws, We1, We2, wb);

    // ---- input projection + pass-1 hidden init ----
    k_gemm_in_mfma<<<gB, b256, 0, stream>>>(x, Wbin, b_in, temp, hb, hidden);

    // ---- GPR pass 1 ----
    {
        const ushort_t* tbl = hb;
        for (int i = 0; i < Ll; ++i) {
            k_gather_agg<<<gW, b256, 0, stream>>>(tbl, rowptr, ep, aggf, sw);
            k_mm64<<<gB, b256, 0, stream>>>(aggf, Wbs + (size_t)i * 512 * 8,
                                            bs + (size_t)i * Hd, sw, temp, i + 1,
                                            hidden, nullptr, curb, 1);
            tbl = curb;
        }
    }

    // ---- edge attention ----
    k_mm64<<<gB, b256, 0, stream>>>(hidden, Wbe1, be1, nullptr, nullptr, 0,
                                    nullptr, aggf, nullptr, 1);
    k_mm64<<<gB, b256, 0, stream>>>(aggf, Wbe2, be2, nullptr, nullptr, 0,
                                    nullptr, nullptr, curb, 0);
    k_edge_attn<<<(Ee * 8) / 256, b256, 0, stream>>>(curb, src, dstI, ew, ew2);
    k_repack<<<gE, b256, 0, stream>>>(ew2, eid, ep);

    // ---- GPR pass 2 ----
    k_init_hidden2<<<gI, b256, 0, stream>>>(hb, hidden, temp);
    {
        const ushort_t* tbl = hb;
        for (int i = 0; i < Ll; ++i) {
            k_gather_agg<<<gW, b256, 0, stream>>>(tbl, rowptr, ep, aggf, sw);
            k_mm64<<<gB, b256, 0, stream>>>(aggf, Wbs + (size_t)i * 512 * 8,
                                            bs + (size_t)i * Hd, sw, temp, i + 1,
                                            hidden, nullptr, curb, 1);
            tbl = curb;
        }
    }

    k_gemm_out<<<(Nn * OUTd + 255) / 256, b256, 0, stream>>>(hidden, W_out, b_out, out);
}